// Round 1
// baseline (523.814 us; speedup 1.0000x reference)
//
#include <hip/hip_runtime.h>

// One thread = one 8x8 image. Memory-bound problem:
//   read 2*B*256B = 512 MiB, write 2*B*16B = 32 MiB -> ~86us floor @6.3TB/s.
// Weights (16x4 each) are wave-uniform -> scalar loads via K$.
// Output layout: [f(img1) (B,4) | f(img2) (B,4)] flat -> dst = out + tid*4.

__global__ __launch_bounds__(256) void surrogate_kernel(
    const float* __restrict__ img1,
    const float* __restrict__ img2,
    const float* __restrict__ Wc,   // (16,4) row-major
    const float* __restrict__ Wl,   // (16,4) row-major
    float* __restrict__ out,
    int B)
{
    const int tid = blockIdx.x * 256 + threadIdx.x;
    if (tid >= 2 * B) return;

    const float* src = (tid < B) ? (img1 + (size_t)tid * 64)
                                 : (img2 + (size_t)(tid - B) * 64);

    // Load the whole image into registers: 16 x dwordx4, contiguous per lane.
    const float4* s4 = (const float4*)src;
    float x[64];
#pragma unroll
    for (int i = 0; i < 16; ++i) {
        float4 t = s4[i];
        x[4 * i + 0] = t.x;
        x[4 * i + 1] = t.y;
        x[4 * i + 2] = t.z;
        x[4 * i + 3] = t.w;
    }

    const float4* wc4 = (const float4*)Wc;
    const float4* wl4 = (const float4*)Wl;

    // patches[p][k], p = quadrant (TL,TR,BL,BR), k = 4*r + ci within quadrant.
    // global element: row = 4*(p>>1) + r, col = 4*(p&1) + ci
    //   -> x[(8*(p>>1) + 2*r + (p&1))*4 + ci]
    float a1[4][4];
#pragma unroll
    for (int p = 0; p < 4; ++p)
#pragma unroll
        for (int c = 0; c < 4; ++c) a1[p][c] = 0.0f;

#pragma unroll
    for (int r = 0; r < 4; ++r) {
#pragma unroll
        for (int ci = 0; ci < 4; ++ci) {
            const int k = 4 * r + ci;
            const float4 w = wc4[k];   // uniform -> s_load
#pragma unroll
            for (int p = 0; p < 4; ++p) {
                const float e = x[(8 * (p >> 1) + 2 * r + (p & 1)) * 4 + ci];
                a1[p][0] = fmaf(e, w.x, a1[p][0]);
                a1[p][1] = fmaf(e, w.y, a1[p][1]);
                a1[p][2] = fmaf(e, w.z, a1[p][2]);
                a1[p][3] = fmaf(e, w.w, a1[p][3]);
            }
        }
    }

    // relu -> /64 -> clip[-128,127]; row-major flatten (4,4)->16
    float co[16];
#pragma unroll
    for (int p = 0; p < 4; ++p) {
#pragma unroll
        for (int c = 0; c < 4; ++c) {
            float t = fmaxf(a1[p][c], 0.0f) * 0.015625f;  // /64 exact
            co[p * 4 + c] = fminf(fmaxf(t, -128.0f), 127.0f);
        }
    }

    // (16,) @ W_linear(16,4)
    float a2[4] = {0.0f, 0.0f, 0.0f, 0.0f};
#pragma unroll
    for (int j = 0; j < 16; ++j) {
        const float4 w = wl4[j];   // uniform -> s_load
        a2[0] = fmaf(co[j], w.x, a2[0]);
        a2[1] = fmaf(co[j], w.y, a2[1]);
        a2[2] = fmaf(co[j], w.z, a2[2]);
        a2[3] = fmaf(co[j], w.w, a2[3]);
    }

    float4 o;
    o.x = fminf(fmaxf(a2[0] * 0.015625f, -128.0f), 127.0f);
    o.y = fminf(fmaxf(a2[1] * 0.015625f, -128.0f), 127.0f);
    o.z = fminf(fmaxf(a2[2] * 0.015625f, -128.0f), 127.0f);
    o.w = fminf(fmaxf(a2[3] * 0.015625f, -128.0f), 127.0f);
    ((float4*)out)[tid] = o;
}

extern "C" void kernel_launch(void* const* d_in, const int* in_sizes, int n_in,
                              void* d_out, int out_size, void* d_ws, size_t ws_size,
                              hipStream_t stream) {
    const float* img1 = (const float*)d_in[0];
    const float* img2 = (const float*)d_in[1];
    const float* Wc   = (const float*)d_in[2];
    const float* Wl   = (const float*)d_in[3];
    float* out = (float*)d_out;

    const int B = in_sizes[0] / 64;        // images per input
    const int total = 2 * B;               // total threads (one per image)
    dim3 grid((total + 255) / 256), block(256);
    hipLaunchKernelGGL(surrogate_kernel, grid, block, 0, stream,
                       img1, img2, Wc, Wl, out, B);
}

// Round 2
// 520.618 us; speedup vs baseline: 1.0061x; 1.0061x over previous
//
#include <hip/hip_runtime.h>

// Memory-bound: read 2*B*256B = 512 MiB, write 32 MiB -> ~86 us floor @6.3TB/s.
// Round-1 kernel (1 thread = 1 image, direct loads) hit only 2.4 TB/s because
// every vmem instruction had 64 lanes on 64 distinct cache lines (256 B lane
// stride). Fix: coalesced staging into LDS (1 KiB contiguous per wave per
// instr), XOR-swizzled float4 layout so both write and read phases hit the
// 8-words/bank wave64 minimum (no conflicts), then 1 thread = 1 image compute.

__global__ __launch_bounds__(256) void surrogate_kernel(
    const float* __restrict__ img1, const float* __restrict__ img2,
    const float* __restrict__ Wc,   // (16,4) row-major
    const float* __restrict__ Wl,   // (16,4) row-major
    float* __restrict__ out,
    int B)
{
    // 256 images * 16 float4 chunks = 64 KiB. chunk c of image i lives at
    // tile[i*16 + (c ^ (i & 15))].
    __shared__ float4 tile[256 * 16];

    const int t = threadIdx.x;
    const int blocksPerInput = B >> 8;            // B % 256 == 0 (B = 1<<20)
    int bid = (int)blockIdx.x;
    const int second = bid >= blocksPerInput ? 1 : 0;
    if (second) bid -= blocksPerInput;
    const float4* src4 = (const float4*)(second ? img2 : img1) + (size_t)bid * 4096;

    // ---- stage: fully coalesced global loads (16 lines/instr/wave) ----
    float4 r[16];
#pragma unroll
    for (int k = 0; k < 16; ++k) r[k] = src4[k * 256 + t];

    const int q   = t >> 4;    // == (loaded image) & 15 for every k
    const int cth = t & 15;    // chunk index this thread loaded
#pragma unroll
    for (int k = 0; k < 16; ++k) {
        const int img = 16 * k + q;
        tile[img * 16 + (cth ^ q)] = r[k];        // img & 15 == q
    }
    __syncthreads();

    // ---- compute: thread t owns image t of this block ----
    const float4* wc4 = (const float4*)Wc;
    const float4* wl4 = (const float4*)Wl;

    float a1[4][4];
#pragma unroll
    for (int p = 0; p < 4; ++p)
#pragma unroll
        for (int c = 0; c < 4; ++c) a1[p][c] = 0.0f;

    const int key = t & 15;
    const int base = t * 16;
#pragma unroll
    for (int c = 0; c < 16; ++c) {                // c uniform -> static indices
        const float4 v = tile[base + (c ^ key)];  // chunk c of image t
        const int row = c >> 1;                   // global row 0..7
        const int p   = ((row >> 2) << 1) | (c & 1);  // quadrant TL,TR,BL,BR
        const int rr  = row & 3;                  // row within quadrant
        const float4 w0 = wc4[rr * 4 + 0];
        const float4 w1 = wc4[rr * 4 + 1];
        const float4 w2 = wc4[rr * 4 + 2];
        const float4 w3 = wc4[rr * 4 + 3];
        a1[p][0] = fmaf(v.x, w0.x, a1[p][0]);
        a1[p][1] = fmaf(v.x, w0.y, a1[p][1]);
        a1[p][2] = fmaf(v.x, w0.z, a1[p][2]);
        a1[p][3] = fmaf(v.x, w0.w, a1[p][3]);
        a1[p][0] = fmaf(v.y, w1.x, a1[p][0]);
        a1[p][1] = fmaf(v.y, w1.y, a1[p][1]);
        a1[p][2] = fmaf(v.y, w1.z, a1[p][2]);
        a1[p][3] = fmaf(v.y, w1.w, a1[p][3]);
        a1[p][0] = fmaf(v.z, w2.x, a1[p][0]);
        a1[p][1] = fmaf(v.z, w2.y, a1[p][1]);
        a1[p][2] = fmaf(v.z, w2.z, a1[p][2]);
        a1[p][3] = fmaf(v.z, w2.w, a1[p][3]);
        a1[p][0] = fmaf(v.w, w3.x, a1[p][0]);
        a1[p][1] = fmaf(v.w, w3.y, a1[p][1]);
        a1[p][2] = fmaf(v.w, w3.z, a1[p][2]);
        a1[p][3] = fmaf(v.w, w3.w, a1[p][3]);
    }

    // relu -> /64 -> clip; row-major flatten (4,4) -> 16
    float co[16];
#pragma unroll
    for (int p = 0; p < 4; ++p)
#pragma unroll
        for (int c = 0; c < 4; ++c) {
            float tv = fmaxf(a1[p][c], 0.0f) * 0.015625f;
            co[p * 4 + c] = fminf(fmaxf(tv, -128.0f), 127.0f);
        }

    float a2[4] = {0.0f, 0.0f, 0.0f, 0.0f};
#pragma unroll
    for (int j = 0; j < 16; ++j) {
        const float4 w = wl4[j];
        a2[0] = fmaf(co[j], w.x, a2[0]);
        a2[1] = fmaf(co[j], w.y, a2[1]);
        a2[2] = fmaf(co[j], w.z, a2[2]);
        a2[3] = fmaf(co[j], w.w, a2[3]);
    }

    float4 o;
    o.x = fminf(fmaxf(a2[0] * 0.015625f, -128.0f), 127.0f);
    o.y = fminf(fmaxf(a2[1] * 0.015625f, -128.0f), 127.0f);
    o.z = fminf(fmaxf(a2[2] * 0.015625f, -128.0f), 127.0f);
    o.w = fminf(fmaxf(a2[3] * 0.015625f, -128.0f), 127.0f);
    ((float4*)out)[(size_t)second * B + (size_t)bid * 256 + t] = o;
}

extern "C" void kernel_launch(void* const* d_in, const int* in_sizes, int n_in,
                              void* d_out, int out_size, void* d_ws, size_t ws_size,
                              hipStream_t stream) {
    const float* img1 = (const float*)d_in[0];
    const float* img2 = (const float*)d_in[1];
    const float* Wc   = (const float*)d_in[2];
    const float* Wl   = (const float*)d_in[3];
    float* out = (float*)d_out;

    const int B = in_sizes[0] / 64;              // images per input (1<<20)
    const int blocks = 2 * (B >> 8);             // 256 images per block
    hipLaunchKernelGGL(surrogate_kernel, dim3(blocks), dim3(256), 0, stream,
                       img1, img2, Wc, Wl, out, B);
}